// Round 13
// baseline (155.938 us; speedup 1.0000x reference)
//
#include <hip/hip_runtime.h>
#include <cstdint>
#include <cstddef>

// PConv, round 13: REQUEST-WIDTH attack. Gather one m's entire 2KB in TWO
// full-wave dwordx4 loads (lane = (row l>>2, seg l&3)) -> 32 line-requests/m
// vs 64+ narrow segment-requests in R7/R10/R12 (which were request-invariant,
// explaining R10's null). Stage via wave-private LDS (rows padded to 144B),
// read fragments as ds_read_u16. Rows via per-lane vector load of inds
// (broadcast-coalesced; no SGPR-array dynamic indexing - rule #20).
// 3-slot rotation: rows 4-ahead, gather/streams 2-ahead, LDS write-late.
// Validated 16x16x16bf16_1k compute + store layout unchanged.

namespace {
constexpr int B_   = 2;
constexpr int N_   = 50000;
constexpr int M_   = 50000;
constexpr int KNB  = 16;
constexpr int CIN  = 64;
constexpr int COUT = 67 * 16;      // 1072
constexpr int PAIRS = B_ * M_;     // 100000
constexpr int FELEMS = B_ * N_ * CIN;   // 6,400,000
constexpr int LROW = 72;           // LDS row stride in ushorts (144B, 16B-aligned)
}

typedef unsigned int u32;
typedef float  f32x4   __attribute__((ext_vector_type(4)));
typedef short  short8  __attribute__((ext_vector_type(8)));
typedef short  short4v __attribute__((ext_vector_type(4)));
typedef u32    u32x4   __attribute__((ext_vector_type(4)));
typedef u32    u32x2   __attribute__((ext_vector_type(2)));

struct StageF { float bg[4][8]; float ad[8]; float wf[8]; };
struct IdxS   { int v[16]; };

static __device__ __forceinline__ short8 pack_bf8(const float* x) {
  u32x4 w;
  #pragma unroll
  for (int q = 0; q < 4; ++q)
    w[q] = __builtin_amdgcn_perm(__builtin_bit_cast(u32, x[2*q+1]),
                                 __builtin_bit_cast(u32, x[2*q]),
                                 0x07060302u);
  return __builtin_bit_cast(short8, w);
}

static __device__ __forceinline__ short4v pack_bf4(const float* x) {
  u32x2 w;
  #pragma unroll
  for (int q = 0; q < 2; ++q)
    w[q] = __builtin_amdgcn_perm(__builtin_bit_cast(u32, x[2*q+1]),
                                 __builtin_bit_cast(u32, x[2*q]),
                                 0x07060302u);
  return __builtin_bit_cast(short4v, w);
}

static __device__ __forceinline__ u32 bfrne(float x) {
  u32 u = __builtin_bit_cast(u32, x);
  return (u + 0x7FFFu + ((u >> 16) & 1u)) >> 16;
}

// ---------------- pre-pass: f32 -> bf16 (RNE) table ----------------
__global__ __launch_bounds__(256)
void cvt_feat_bf16(const float* __restrict__ src, unsigned short* __restrict__ dst) {
  const int n4 = FELEMS / 4;
  int i = blockIdx.x * blockDim.x + threadIdx.x;
  const int stride = gridDim.x * blockDim.x;
  const f32x4* s4 = reinterpret_cast<const f32x4*>(src);
  for (; i < n4; i += stride) {
    f32x4 v = s4[i];
    u32x2 w;
    w[0] = bfrne(v[0]) | (bfrne(v[1]) << 16);
    w[1] = bfrne(v[2]) | (bfrne(v[3]) << 16);
    *reinterpret_cast<u32x2*>(dst + 4 * (size_t)i) = w;
  }
}

#if __has_builtin(__builtin_amdgcn_mfma_f32_16x16x16bf16_1k)

__global__ __launch_bounds__(256, 4)
void pconv13(const unsigned short* __restrict__ tbl, const int* __restrict__ inds,
             const float* __restrict__ wnet, const float* __restrict__ addf,
             float* __restrict__ out)
{
  __shared__ alignas(16) unsigned short sg[4][16 * LROW];  // 2.3KB per wave
  const int lane = threadIdx.x & 63;
  const int wid  = threadIdx.x >> 6;
  unsigned short* __restrict__ lds = &sg[wid][0];
  const int cc = lane & 15, g = lane >> 4;         // compute role
  const int r_ = lane >> 2, s_ = lane & 3;         // gather role
  const int gw = __builtin_amdgcn_readfirstlane(
      (int)((blockIdx.x * blockDim.x + threadIdx.x) >> 6));
  const int nw = (int)((gridDim.x * blockDim.x) >> 6);
  if (gw >= PAIRS) return;

#define CLQ(x) (((x) < PAIRS) ? (x) : gw)

  int   row0, row1, row2;                          // per-lane neighbor rows
  u32x4 ga0, gb0, ga1, gb1, ga2, gb2;              // gathered 2x16B per slot
  float wf0[4], wf1[4], wf2[4], ad0[4], ad1[4], ad2[4];

  // per-lane row load: lanes 4k..4k+3 share an address (broadcast-coalesced)
#define ROWL(R, q) do { const int _q = CLQ(q); \
      R = inds[(size_t)_q * KNB + r_]; } while (0)

  // two full-wave dwordx4 gathers cover the whole 16x128B tile for m=q
#define GATH(Sa, Sb, R, q) do { const int _q = CLQ(q); \
      const unsigned short* __restrict__ _fb = tbl + ((_q >= M_) ? (size_t)N_ * CIN : 0) \
          + (((u32)(R)) << 6) + (u32)(s_ * 8); \
      Sa = *reinterpret_cast<const u32x4*>(_fb); \
      Sb = *reinterpret_cast<const u32x4*>(_fb + 32); } while (0)

#define STRM(WF, AD, q) do { const int _q = CLQ(q); \
      const float* __restrict__ _wp = wnet + (size_t)_q * 256 + g * 64 + cc; \
      WF[0] = __builtin_nontemporal_load(_wp); \
      WF[1] = __builtin_nontemporal_load(_wp + 16); \
      WF[2] = __builtin_nontemporal_load(_wp + 32); \
      WF[3] = __builtin_nontemporal_load(_wp + 48); \
      const float* __restrict__ _ap = addf + (size_t)_q * 48 + g * 12 + cc; \
      AD[0] = (cc < 3) ? __builtin_nontemporal_load(_ap)     : 0.f; \
      AD[1] = (cc < 3) ? __builtin_nontemporal_load(_ap + 3) : 0.f; \
      AD[2] = (cc < 3) ? __builtin_nontemporal_load(_ap + 6) : 0.f; \
      AD[3] = (cc < 3) ? __builtin_nontemporal_load(_ap + 9) : 0.f; } while (0)

#define WRIT(Sa, Sb) do { \
      *reinterpret_cast<u32x4*>(lds + r_ * LROW + s_ * 8)      = Sa; \
      *reinterpret_cast<u32x4*>(lds + r_ * LROW + s_ * 8 + 32) = Sb; } while (0)

#define COMP(WF, AD, pp) do { \
      float* __restrict__ _op = out + (size_t)(pp) * COUT; \
      const short4v _a = pack_bf4(WF); \
      const int _soff = cc * 16 + g * 4; \
      _Pragma("unroll") \
      for (int t = 0; t < 4; ++t) { \
        const int _cb = t * 16 + cc; \
        const u32 _e0 = lds[(4 * g + 0) * LROW + _cb]; \
        const u32 _e1 = lds[(4 * g + 1) * LROW + _cb]; \
        const u32 _e2 = lds[(4 * g + 2) * LROW + _cb]; \
        const u32 _e3 = lds[(4 * g + 3) * LROW + _cb]; \
        u32x2 _w; _w[0] = _e0 | (_e1 << 16); _w[1] = _e2 | (_e3 << 16); \
        const short4v _bb = __builtin_bit_cast(short4v, _w); \
        f32x4 _acc = {0.f, 0.f, 0.f, 0.f}; \
        _acc = __builtin_amdgcn_mfma_f32_16x16x16bf16_1k(_a, _bb, _acc, 0, 0, 0); \
        __builtin_nontemporal_store(_acc, reinterpret_cast<f32x4*>(_op + _soff + t * 256)); \
      } \
      { const short4v _bb = pack_bf4(AD); \
        f32x4 _acc = {0.f, 0.f, 0.f, 0.f}; \
        _acc = __builtin_amdgcn_mfma_f32_16x16x16bf16_1k(_a, _bb, _acc, 0, 0, 0); \
        if (cc < 3) \
          __builtin_nontemporal_store(_acc, reinterpret_cast<f32x4*>(_op + _soff + 1024)); \
      } } while (0)

  int p = gw;
  // prologue: rows for p..p+2, gathers for p..p+1, refill row0 with p+3, streams p..p+1
  ROWL(row0, p); ROWL(row1, p + nw); ROWL(row2, p + 2 * nw);
  GATH(ga0, gb0, row0, p);
  GATH(ga1, gb1, row1, p + nw);
  ROWL(row0, p + 3 * nw);
  STRM(wf0, ad0, p);
  STRM(wf1, ad1, p + nw);

  while (true) {
    { // phase 0: consume slot0
      ROWL(row1, p + 4 * nw);
      GATH(ga2, gb2, row2, p + 2 * nw);
      STRM(wf2, ad2, p + 2 * nw);
      WRIT(ga0, gb0);
      COMP(wf0, ad0, p);
      p += nw; if (p >= PAIRS) break;
    }
    { // phase 1: consume slot1
      ROWL(row2, p + 4 * nw);
      GATH(ga0, gb0, row0, p + 2 * nw);
      STRM(wf0, ad0, p + 2 * nw);
      WRIT(ga1, gb1);
      COMP(wf1, ad1, p);
      p += nw; if (p >= PAIRS) break;
    }
    { // phase 2: consume slot2
      ROWL(row0, p + 4 * nw);
      GATH(ga1, gb1, row1, p + 2 * nw);
      STRM(wf1, ad1, p + 2 * nw);
      WRIT(ga2, gb2);
      COMP(wf2, ad2, p);
      p += nw; if (p >= PAIRS) break;
    }
  }

#undef CLQ
#undef ROWL
#undef GATH
#undef STRM
#undef WRIT
#undef COMP
}

#else  // builtin absent: proven R7 structure (x32 MFMA, 1-deep)

struct StageT { unsigned short bg[4][8]; float ad[8]; float wf[8]; };

static __device__ __forceinline__ void load_idx_s(const int* __restrict__ idxp, IdxS& r) {
  #pragma unroll
  for (int j = 0; j < 16; ++j)
    r.v[j] = __builtin_amdgcn_readfirstlane(idxp[j]);
}

static __device__ __forceinline__ void load_stage_t(const unsigned short* __restrict__ fb,
                                                    const float* __restrict__ wnp,
                                                    const float* __restrict__ adp,
                                                    const IdxS& I, int lane, StageT& S) {
  const int cc = lane & 15;
  if (lane < 32) {
    const int hi = lane >> 4;
    int rows[8];
    #pragma unroll
    for (int j = 0; j < 8; ++j) rows[j] = hi ? I.v[j + 8] : I.v[j];
    #pragma unroll
    for (int j = 0; j < 8; ++j) {
      const u32 rb = ((u32)rows[j]) << 6;
      #pragma unroll
      for (int t = 0; t < 4; ++t)
        S.bg[t][j] = fb[rb + (u32)(t * 16 + cc)];
    }
    const u32 woff = (hi ? 128u : 0u) + (u32)cc;
    #pragma unroll
    for (int j = 0; j < 8; ++j)
      S.wf[j] = __builtin_nontemporal_load(wnp + woff + j * 16);
    if (cc < 3) {
      const u32 aoff = (hi ? 24u : 0u) + (u32)cc;
      #pragma unroll
      for (int j = 0; j < 8; ++j)
        S.ad[j] = __builtin_nontemporal_load(adp + aoff + j * 3);
    }
  }
}

__global__ __launch_bounds__(256, 4)
void pconv13(const unsigned short* __restrict__ tbl, const int* __restrict__ inds,
             const float* __restrict__ wnet, const float* __restrict__ addf,
             float* __restrict__ out)
{
  const int lane = threadIdx.x & 63;
  const int gw = __builtin_amdgcn_readfirstlane(
      (int)((blockIdx.x * blockDim.x + threadIdx.x) >> 6));
  const int nw = (int)((gridDim.x * blockDim.x) >> 6);
  if (gw >= PAIRS) return;

  IdxS iCur, iNext;
  load_idx_s(inds + (size_t)gw * KNB, iCur);
  for (int p = gw; p < PAIRS; p += nw) {
    const int pn = (p + nw < PAIRS) ? (p + nw) : gw;
    load_idx_s(inds + (size_t)pn * KNB, iNext);
    const int b = (p >= M_) ? 1 : 0;
    StageT S = {};
    load_stage_t(tbl + (size_t)b * N_ * CIN, wnet + (size_t)p * 256,
                 addf + (size_t)p * 48, iCur, lane, S);
    const int cc = lane & 15, g = lane >> 4;
    const int soff = cc * 16 + g * 4;
    float* op = out + (size_t)p * COUT;
    const short8 a = pack_bf8(S.wf);
    #pragma unroll
    for (int t = 0; t < 4; ++t) {
      short8 bb;
      #pragma unroll
      for (int j = 0; j < 8; ++j) bb[j] = (short)S.bg[t][j];
      f32x4 acc = {0.f, 0.f, 0.f, 0.f};
      acc = __builtin_amdgcn_mfma_f32_16x16x32_bf16(a, bb, acc, 0, 0, 0);
      __builtin_nontemporal_store(acc, reinterpret_cast<f32x4*>(op + soff + t * 256));
    }
    {
      const short8 bb = pack_bf8(S.ad);
      f32x4 acc = {0.f, 0.f, 0.f, 0.f};
      acc = __builtin_amdgcn_mfma_f32_16x16x32_bf16(a, bb, acc, 0, 0, 0);
      if (cc < 3)
        __builtin_nontemporal_store(acc, reinterpret_cast<f32x4*>(op + soff + 1024));
    }
    #pragma unroll
    for (int j = 0; j < 16; ++j) iCur.v[j] = iNext.v[j];
  }
}

#endif  // __has_builtin

// ---------------- fallback (ws too small): proven R7-f32 single pass ----------------
static __device__ __forceinline__ void load_idx_f(const int* __restrict__ idxp, IdxS& r) {
  #pragma unroll
  for (int j = 0; j < 16; ++j)
    r.v[j] = __builtin_amdgcn_readfirstlane(idxp[j]);
}

static __device__ __forceinline__ void load_stage_f(const float* __restrict__ fb,
                                                    const float* __restrict__ wnp,
                                                    const float* __restrict__ adp,
                                                    const IdxS& I, int lane, StageF& S) {
  const int cc = lane & 15;
  if (lane < 32) {
    const int hi = lane >> 4;
    int rows[8];
    #pragma unroll
    for (int j = 0; j < 8; ++j) rows[j] = hi ? I.v[j + 8] : I.v[j];
    #pragma unroll
    for (int j = 0; j < 8; ++j) {
      const u32 rb = ((u32)rows[j]) << 6;
      #pragma unroll
      for (int t = 0; t < 4; ++t)
        S.bg[t][j] = fb[rb + (u32)(t * 16 + cc)];
    }
    const u32 woff = (hi ? 128u : 0u) + (u32)cc;
    #pragma unroll
    for (int j = 0; j < 8; ++j)
      S.wf[j] = __builtin_nontemporal_load(wnp + woff + j * 16);
    if (cc < 3) {
      const u32 aoff = (hi ? 24u : 0u) + (u32)cc;
      #pragma unroll
      for (int j = 0; j < 8; ++j)
        S.ad[j] = __builtin_nontemporal_load(adp + aoff + j * 3);
    }
  }
}

__global__ __launch_bounds__(256, 4)
void pconv13_f32(const float* __restrict__ feat, const int* __restrict__ inds,
                 const float* __restrict__ wnet, const float* __restrict__ addf,
                 float* __restrict__ out)
{
  const int lane = threadIdx.x & 63;
  const int gw = __builtin_amdgcn_readfirstlane(
      (int)((blockIdx.x * blockDim.x + threadIdx.x) >> 6));
  const int nw = (int)((gridDim.x * blockDim.x) >> 6);
  if (gw >= PAIRS) return;

  IdxS iCur, iNext;
  load_idx_f(inds + (size_t)gw * KNB, iCur);
  for (int p = gw; p < PAIRS; p += nw) {
    const int pn = (p + nw < PAIRS) ? (p + nw) : gw;
    load_idx_f(inds + (size_t)pn * KNB, iNext);
    const int b = (p >= M_) ? 1 : 0;
    StageF S = {};
    load_stage_f(feat + (size_t)b * N_ * CIN, wnet + (size_t)p * 256,
                 addf + (size_t)p * 48, iCur, lane, S);
    const int cc = lane & 15, g = lane >> 4;
    const int soff = cc * 16 + g * 4;
    float* op = out + (size_t)p * COUT;
    const short8 a = pack_bf8(S.wf);
    #pragma unroll
    for (int t = 0; t < 4; ++t) {
      const short8 bb = pack_bf8(S.bg[t]);
      f32x4 acc = {0.f, 0.f, 0.f, 0.f};
      acc = __builtin_amdgcn_mfma_f32_16x16x32_bf16(a, bb, acc, 0, 0, 0);
      __builtin_nontemporal_store(acc, reinterpret_cast<f32x4*>(op + soff + t * 256));
    }
    {
      const short8 bb = pack_bf8(S.ad);
      f32x4 acc = {0.f, 0.f, 0.f, 0.f};
      acc = __builtin_amdgcn_mfma_f32_16x16x32_bf16(a, bb, acc, 0, 0, 0);
      if (cc < 3)
        __builtin_nontemporal_store(acc, reinterpret_cast<f32x4*>(op + soff + 1024));
    }
    #pragma unroll
    for (int j = 0; j < 16; ++j) iCur.v[j] = iNext.v[j];
  }
}

extern "C" void kernel_launch(void* const* d_in, const int* in_sizes, int n_in,
                              void* d_out, int out_size, void* d_ws, size_t ws_size,
                              hipStream_t stream) {
  const float* feat = (const float*)d_in[0];
  const int*   inds = (const int*)d_in[1];
  const float* wnet = (const float*)d_in[2];
  const float* addf = (const float*)d_in[3];
  float* outp = (float*)d_out;

  const size_t TBL_BYTES = (size_t)FELEMS * sizeof(unsigned short);  // 12.8 MB

  dim3 grid(1024), block(256);   // 4 blocks/CU resident; ~24 iters/wave
  if (ws_size >= TBL_BYTES) {
    unsigned short* tbl = (unsigned short*)d_ws;
    hipLaunchKernelGGL(cvt_feat_bf16, dim3(2048), dim3(256), 0, stream, feat, tbl);
    hipLaunchKernelGGL(pconv13, grid, block, 0, stream, tbl, inds, wnet, addf, outp);
  } else {
    hipLaunchKernelGGL(pconv13_f32, grid, block, 0, stream,
                       feat, inds, wnet, addf, outp);
  }
}